// Round 2
// baseline (2928.727 us; speedup 1.0000x reference)
//
#include <hip/hip_runtime.h>

#define NC 100000
#define NF 400000
#define NE 1600000
#define C  64

// Persistent grid-stride scatter: each thread handles 4 channels (float4) of
// an edge per iteration; 16 threads cover an edge row. 2048 blocks x 256
// threads fill the machine exactly (4 waves/block, ~32 waves/CU); each thread
// loops ~49 times -> wave count 1.6M -> 8k.
__global__ __launch_bounds__(256) void k_scatter(
    const float* __restrict__ x, const int* __restrict__ src,
    const int* __restrict__ dst, const float* __restrict__ w,
    float* __restrict__ out, int nEdges)
{
    const int nthreads = gridDim.x * 256;
    const int total = nEdges * 16;                 // 25.6M < 2^31
    for (int idx = blockIdx.x * 256 + threadIdx.x; idx < total; idx += nthreads) {
        int e = idx >> 4;
        int q = (idx & 15) << 2;                   // channel offset 0..60
        float we = w[e];
        const float4 xv = *(const float4*)(x + src[e] * C + q);
        float* o = out + dst[e] * C + q;
        atomicAdd(o + 0, we * xv.x);
        atomicAdd(o + 1, we * xv.y);
        atomicAdd(o + 2, we * xv.z);
        atomicAdd(o + 3, we * xv.w);
    }
}

// h = agg @ W + b. W staged once in LDS (16 KiB), then 64 rows per block:
// 4 waves x 16 rows each, lane = output column. Work:staging = 262k FMA : 4k.
__global__ __launch_bounds__(256) void k_gemm(
    const float* __restrict__ agg, const float* __restrict__ W,
    const float* __restrict__ b, float* __restrict__ h)
{
    __shared__ float Ws[64 * 64];
    int tid = threadIdx.x;
    #pragma unroll
    for (int i = 0; i < 16; ++i) Ws[i * 256 + tid] = W[i * 256 + tid];
    __syncthreads();
    int c = tid & 63;
    float bc = b[c];
    for (int r = tid >> 6; r < 64; r += 4) {
        int row = blockIdx.x * 64 + r;
        if (row >= NC) break;
        const float* __restrict__ ar = agg + (size_t)row * C;
        float acc = bc;
        #pragma unroll
        for (int k = 0; k < 64; ++k) acc = fmaf(ar[k], Ws[k * 64 + c], acc);
        h[(size_t)row * C + c] = acc;
    }
}

// out[fwd[i]] = h[i]  (overwrite; fwd rows unique). float4 per thread.
__global__ __launch_bounds__(256) void k_inject(
    const float* __restrict__ h, const int* __restrict__ fwd,
    float* __restrict__ out)
{
    int idx = blockIdx.x * 256 + threadIdx.x;      // NC*16 total
    if (idx >= NC * 16) return;
    int i = idx >> 4;
    int q = (idx & 15) << 2;
    *(float4*)(out + fwd[i] * C + q) = *(const float4*)(h + i * C + q);
}

extern "C" void kernel_launch(void* const* d_in, const int* in_sizes, int n_in,
                              void* d_out, int out_size, void* d_ws, size_t ws_size,
                              hipStream_t stream) {
    const float* x    = (const float*)d_in[0];
    const float* W    = (const float*)d_in[1];
    const float* b    = (const float*)d_in[2];
    const int*   ei   = (const int*)d_in[3];   // [2,E] flat: src = ei, dst = ei+E
    const float* ea   = (const float*)d_in[4];
    const int*   psrc = (const int*)d_in[5];
    const int*   pdst = (const int*)d_in[6];
    const float* pw   = (const float*)d_in[7];
    const int*   fwd  = (const int*)d_in[8];
    float* out = (float*)d_out;

    float* agg = (float*)d_ws;                  // NC*C fp32 = 25.6 MB
    float* h   = agg + (size_t)NC * C;          // NC*C fp32 = 25.6 MB

    hipMemsetAsync(agg, 0, (size_t)NC * C * sizeof(float), stream);
    hipMemsetAsync(out, 0, (size_t)NF * C * sizeof(float), stream);

    const int SC_BLOCKS = 2048;                 // 8 blocks/CU x 256 CUs
    k_scatter<<<SC_BLOCKS, 256, 0, stream>>>(x, ei, ei + NE, ea, agg, NE);
    k_gemm<<<(NC + 63) / 64, 256, 0, stream>>>(agg, W, b, h);
    k_scatter<<<SC_BLOCKS, 256, 0, stream>>>(h, psrc, pdst, pw, out, NE);
    k_inject<<<(NC * 16 + 255) / 256, 256, 0, stream>>>(h, fwd, out);
}

// Round 3
// 871.171 us; speedup vs baseline: 3.3618x; 3.3618x over previous
//
#include <hip/hip_runtime.h>

#define NC 100000
#define NF 400000
#define NE 1600000
#define C  64

// ---------------- CSR build: histogram -> scan -> place ----------------

__global__ __launch_bounds__(256) void k_hist(
    const int* __restrict__ dst, int* __restrict__ cnt, int nE)
{
    int stride = gridDim.x * 256;
    for (int e = blockIdx.x * 256 + threadIdx.x; e < nE; e += stride)
        atomicAdd(&cnt[dst[e]], 1);
}

// Per-1024-chunk sums.
__global__ __launch_bounds__(256) void k_chunk_sum(
    const int* __restrict__ cnt, int n, int* __restrict__ chunks)
{
    __shared__ int sd[256];
    int t = threadIdx.x;
    int base = blockIdx.x * 1024 + t * 4;
    int s = 0;
    #pragma unroll
    for (int i = 0; i < 4; ++i) if (base + i < n) s += cnt[base + i];
    sd[t] = s; __syncthreads();
    for (int off = 128; off > 0; off >>= 1) {
        if (t < off) sd[t] += sd[t + off];
        __syncthreads();
    }
    if (t == 0) chunks[blockIdx.x] = sd[0];
}

// Exclusive scan of chunk sums (single block, <=512 chunks).
__global__ __launch_bounds__(512) void k_scan_chunks(
    const int* __restrict__ chunks, int* __restrict__ chunkoff, int nChunks)
{
    __shared__ int sd[512];
    int t = threadIdx.x;
    int v = (t < nChunks) ? chunks[t] : 0;
    sd[t] = v; __syncthreads();
    for (int off = 1; off < 512; off <<= 1) {
        int tv = sd[t];
        if (t >= off) tv += sd[t - off];
        __syncthreads();
        sd[t] = tv; __syncthreads();
    }
    if (t < nChunks) chunkoff[t] = sd[t] - v;   // exclusive
}

// Final: per-chunk intra-scan + chunk offset -> start[]; start[n] = nE.
__global__ __launch_bounds__(256) void k_scan_final(
    const int* __restrict__ cnt, const int* __restrict__ chunkoff,
    int* __restrict__ start, int n, int nE)
{
    __shared__ int sd[256];
    int t = threadIdx.x;
    int base = blockIdx.x * 1024 + t * 4;
    int v[4];
    #pragma unroll
    for (int i = 0; i < 4; ++i) v[i] = (base + i < n) ? cnt[base + i] : 0;
    int tsum = v[0] + v[1] + v[2] + v[3];
    sd[t] = tsum; __syncthreads();
    for (int off = 1; off < 256; off <<= 1) {
        int tv = sd[t];
        if (t >= off) tv += sd[t - off];
        __syncthreads();
        sd[t] = tv; __syncthreads();
    }
    int off = chunkoff[blockIdx.x] + sd[t] - tsum;
    #pragma unroll
    for (int i = 0; i < 4; ++i) {
        if (base + i < n) { start[base + i] = off; off += v[i]; }
    }
    if (blockIdx.x == 0 && t == 0) start[n] = nE;
}

// Place edge records (src, weight) into dst-sorted order. cnt must be 0.
__global__ __launch_bounds__(256) void k_place(
    const int* __restrict__ dst, const int* __restrict__ src,
    const float* __restrict__ w, const int* __restrict__ start,
    int* __restrict__ cnt, int2* __restrict__ rec, int nE)
{
    int stride = gridDim.x * 256;
    for (int e = blockIdx.x * 256 + threadIdx.x; e < nE; e += stride) {
        int d = dst[e];
        int p = start[d] + atomicAdd(&cnt[d], 1);
        rec[p] = make_int2(src[e], __float_as_int(w[e]));
    }
}

// ---------------- Fused coarse gather + GEMM + bias -> h ----------------
// One wave per coarse node: lanes = channels. Gather agg row in registers,
// then h[c] = b[c] + sum_k agg[k]*W[k][c] via readlane broadcast + LDS W.
__global__ __launch_bounds__(256) void k_gather_gemm(
    const float* __restrict__ x, const int2* __restrict__ rec,
    const int* __restrict__ start, const float* __restrict__ W,
    const float* __restrict__ b, float* __restrict__ h)
{
    __shared__ float Ws[64 * 64];
    int tid = threadIdx.x;
    #pragma unroll
    for (int i = 0; i < 16; ++i) Ws[i * 256 + tid] = W[i * 256 + tid];
    __syncthreads();

    int lane = tid & 63;
    int wv = (blockIdx.x * 256 + tid) >> 6;
    int nW = gridDim.x * 4;
    float bl = b[lane];
    for (int n = wv; n < NC; n += nW) {
        int s = start[n], e = start[n + 1];
        float acc = 0.f;
        for (int j = s; j < e; ++j) {
            int2 r = rec[j];   // wave-uniform address -> broadcast
            acc = fmaf(__int_as_float(r.y), x[(size_t)r.x * C + lane], acc);
        }
        float hv = bl;
        #pragma unroll
        for (int k = 0; k < 64; ++k) {
            float ak = __int_as_float(__builtin_amdgcn_readlane(__float_as_int(acc), k));
            hv = fmaf(ak, Ws[k * 64 + lane], hv);
        }
        h[(size_t)n * C + lane] = hv;
    }
}

// inv[fwd[i]] = i  (inv pre-set to -1)
__global__ __launch_bounds__(256) void k_inv(
    const int* __restrict__ fwd, int* __restrict__ inv)
{
    int i = blockIdx.x * 256 + threadIdx.x;
    if (i < NC) inv[fwd[i]] = i;
}

// ---------------- Fine gather with injection folded in ----------------
// One wave per fine node. Injection targets copy h row and skip their edges.
__global__ __launch_bounds__(256) void k_gather_fine(
    const float* __restrict__ h, const int2* __restrict__ rec,
    const int* __restrict__ start, const int* __restrict__ inv,
    float* __restrict__ out)
{
    int tid = threadIdx.x;
    int lane = tid & 63;
    int wv = (blockIdx.x * 256 + tid) >> 6;
    int nW = gridDim.x * 4;
    for (int n = wv; n < NF; n += nW) {
        int iv = inv[n];
        float val;
        if (iv >= 0) {
            val = h[(size_t)iv * C + lane];
        } else {
            int s = start[n], e = start[n + 1];
            val = 0.f;
            for (int j = s; j < e; ++j) {
                int2 r = rec[j];
                val = fmaf(__int_as_float(r.y), h[(size_t)r.x * C + lane], val);
            }
        }
        out[(size_t)n * C + lane] = val;
    }
}

extern "C" void kernel_launch(void* const* d_in, const int* in_sizes, int n_in,
                              void* d_out, int out_size, void* d_ws, size_t ws_size,
                              hipStream_t stream) {
    const float* x    = (const float*)d_in[0];
    const float* W    = (const float*)d_in[1];
    const float* b    = (const float*)d_in[2];
    const int*   ei   = (const int*)d_in[3];   // [2,E]: src = ei, dst = ei+NE
    const float* ea   = (const float*)d_in[4];
    const int*   psrc = (const int*)d_in[5];
    const int*   pdst = (const int*)d_in[6];
    const float* pw   = (const float*)d_in[7];
    const int*   fwd  = (const int*)d_in[8];
    float* out = (float*)d_out;

    // Workspace layout (~43 MB)
    char* p = (char*)d_ws;
    float* h      = (float*)p;            p += (size_t)NC * C * sizeof(float);   // 25.6 MB
    int2*  rec    = (int2*)p;             p += (size_t)NE * sizeof(int2);        // 12.8 MB
    int*   start  = (int*)p;              p += (size_t)(NF + 1) * sizeof(int);   // 1.6 MB
    int*   cnt    = (int*)p;              p += (size_t)NF * sizeof(int);         // 1.6 MB
    int*   inv    = (int*)p;              p += (size_t)NF * sizeof(int);         // 1.6 MB
    int*   chunks = (int*)p;              p += 512 * sizeof(int);
    int*   choff  = (int*)p;

    const int GS = 2048;   // persistent grids: 8 blocks/CU

    // ---- Stage 1: CSR over coarse dst, fused gather+gemm -> h ----
    {
        int nChunks = (NC + 1023) / 1024;   // 98
        hipMemsetAsync(cnt, 0, (size_t)NC * sizeof(int), stream);
        k_hist<<<GS, 256, 0, stream>>>(ei + NE, cnt, NE);
        k_chunk_sum<<<nChunks, 256, 0, stream>>>(cnt, NC, chunks);
        k_scan_chunks<<<1, 512, 0, stream>>>(chunks, choff, nChunks);
        k_scan_final<<<nChunks, 256, 0, stream>>>(cnt, choff, start, NC, NE);
        hipMemsetAsync(cnt, 0, (size_t)NC * sizeof(int), stream);
        k_place<<<GS, 256, 0, stream>>>(ei + NE, ei, ea, start, cnt, rec, NE);
        k_gather_gemm<<<GS, 256, 0, stream>>>(x, rec, start, W, b, h);
    }

    // ---- Stage 2: CSR over fine dst, gather with injection fold -> out ----
    {
        int nChunks = (NF + 1023) / 1024;   // 391
        hipMemsetAsync(cnt, 0, (size_t)NF * sizeof(int), stream);
        k_hist<<<GS, 256, 0, stream>>>(pdst, cnt, NE);
        k_chunk_sum<<<nChunks, 256, 0, stream>>>(cnt, NF, chunks);
        k_scan_chunks<<<1, 512, 0, stream>>>(chunks, choff, nChunks);
        k_scan_final<<<nChunks, 256, 0, stream>>>(cnt, choff, start, NF, NE);
        hipMemsetAsync(cnt, 0, (size_t)NF * sizeof(int), stream);
        k_place<<<GS, 256, 0, stream>>>(pdst, psrc, pw, start, cnt, rec, NE);
        hipMemsetAsync(inv, 0xFF, (size_t)NF * sizeof(int), stream);
        k_inv<<<(NC + 255) / 256, 256, 0, stream>>>(fwd, inv);
        k_gather_fine<<<GS, 256, 0, stream>>>(h, rec, start, inv, out);
    }
}

// Round 4
// 673.272 us; speedup vs baseline: 4.3500x; 1.2939x over previous
//
#include <hip/hip_runtime.h>

#define NC 100000
#define NF 400000
#define NE 1600000
#define NT (NC + NF)            // 500000 combined nodes
#define C  64

// ---------------- Fused CSR build over combined node space ----------------
// Coarse dst -> node ids [0, NC); fine dst -> [NC, NC+NF).

__global__ __launch_bounds__(256) void k_hist2(
    const int* __restrict__ cd, const int* __restrict__ pd,
    int* __restrict__ cnt)
{
    int stride = gridDim.x * 256;
    const int total = 2 * NE;
    for (int e = blockIdx.x * 256 + threadIdx.x; e < total; e += stride) {
        int d = (e < NE) ? cd[e] : (NC + pd[e - NE]);
        atomicAdd(&cnt[d], 1);
    }
}

__global__ __launch_bounds__(256) void k_chunk_sum(
    const int* __restrict__ cnt, int n, int* __restrict__ chunks)
{
    __shared__ int sd[256];
    int t = threadIdx.x;
    int base = blockIdx.x * 1024 + t * 4;
    int s = 0;
    #pragma unroll
    for (int i = 0; i < 4; ++i) if (base + i < n) s += cnt[base + i];
    sd[t] = s; __syncthreads();
    for (int off = 128; off > 0; off >>= 1) {
        if (t < off) sd[t] += sd[t + off];
        __syncthreads();
    }
    if (t == 0) chunks[blockIdx.x] = sd[0];
}

__global__ __launch_bounds__(512) void k_scan_chunks(
    const int* __restrict__ chunks, int* __restrict__ chunkoff, int nChunks)
{
    __shared__ int sd[512];
    int t = threadIdx.x;
    int v = (t < nChunks) ? chunks[t] : 0;
    sd[t] = v; __syncthreads();
    for (int off = 1; off < 512; off <<= 1) {
        int tv = sd[t];
        if (t >= off) tv += sd[t - off];
        __syncthreads();
        sd[t] = tv; __syncthreads();
    }
    if (t < nChunks) chunkoff[t] = sd[t] - v;   // exclusive
}

__global__ __launch_bounds__(256) void k_scan_final(
    const int* __restrict__ cnt, const int* __restrict__ chunkoff,
    int* __restrict__ start, int n, int nE)
{
    __shared__ int sd[256];
    int t = threadIdx.x;
    int base = blockIdx.x * 1024 + t * 4;
    int v[4];
    #pragma unroll
    for (int i = 0; i < 4; ++i) v[i] = (base + i < n) ? cnt[base + i] : 0;
    int tsum = v[0] + v[1] + v[2] + v[3];
    sd[t] = tsum; __syncthreads();
    for (int off = 1; off < 256; off <<= 1) {
        int tv = sd[t];
        if (t >= off) tv += sd[t - off];
        __syncthreads();
        sd[t] = tv; __syncthreads();
    }
    int off = chunkoff[blockIdx.x] + sd[t] - tsum;
    #pragma unroll
    for (int i = 0; i < 4; ++i) {
        if (base + i < n) { start[base + i] = off; off += v[i]; }
    }
    if (blockIdx.x == 0 && t == 0) start[n] = nE;
}

__global__ __launch_bounds__(256) void k_place2(
    const int* __restrict__ cd, const int* __restrict__ csrc, const float* __restrict__ cw,
    const int* __restrict__ pd, const int* __restrict__ psrc, const float* __restrict__ pw,
    const int* __restrict__ start, int* __restrict__ cnt, int2* __restrict__ rec)
{
    int stride = gridDim.x * 256;
    const int total = 2 * NE;
    for (int e = blockIdx.x * 256 + threadIdx.x; e < total; e += stride) {
        int d, s; float w;
        if (e < NE) { d = cd[e]; s = csrc[e]; w = cw[e]; }
        else { int f = e - NE; d = NC + pd[f]; s = psrc[f]; w = pw[f]; }
        int p = start[d] + atomicAdd(&cnt[d], 1);
        rec[p] = make_int2(s, __float_as_int(w));
    }
}

// ---------------- Gathers: quarter-wave float4, 8 gathers in flight ----------------
// lane = 16*(quarter) + i; lane i covers channels [4i, 4i+4). Quarter q walks
// edge pairs {s+2q, s+2q+1}, stride 8 -> up to 8 independent gathers/wave.
// Cross-quarter sum via shfl_xor(16), shfl_xor(32); quarter 0 writes the row.

__global__ __launch_bounds__(256) void k_gather_coarse(
    const float* __restrict__ x, const int2* __restrict__ rec,
    const int* __restrict__ start, float* __restrict__ agg)
{
    int tid = threadIdx.x;
    int lane = tid & 63;
    int q = lane >> 4;
    int c4 = (lane & 15) << 2;
    int wv = (blockIdx.x * 256 + tid) >> 6;
    int nW = gridDim.x * 4;
    for (int n = wv; n < NC; n += nW) {
        int s = start[n], e = start[n + 1];
        float ax = 0.f, ay = 0.f, az = 0.f, aw = 0.f;
        for (int j = s + 2 * q; j < e; j += 8) {
            int2 r0 = rec[j];
            int j1 = j + 1;
            int2 r1 = (j1 < e) ? rec[j1] : make_int2(0, 0);
            float4 v0 = *(const float4*)(x + (size_t)r0.x * C + c4);
            float w0 = __int_as_float(r0.y);
            ax = fmaf(w0, v0.x, ax); ay = fmaf(w0, v0.y, ay);
            az = fmaf(w0, v0.z, az); aw = fmaf(w0, v0.w, aw);
            if (j1 < e) {
                float4 v1 = *(const float4*)(x + (size_t)r1.x * C + c4);
                float w1 = __int_as_float(r1.y);
                ax = fmaf(w1, v1.x, ax); ay = fmaf(w1, v1.y, ay);
                az = fmaf(w1, v1.z, az); aw = fmaf(w1, v1.w, aw);
            }
        }
        ax += __shfl_xor(ax, 16); ay += __shfl_xor(ay, 16);
        az += __shfl_xor(az, 16); aw += __shfl_xor(aw, 16);
        ax += __shfl_xor(ax, 32); ay += __shfl_xor(ay, 32);
        az += __shfl_xor(az, 32); aw += __shfl_xor(aw, 32);
        if (q == 0)
            *(float4*)(agg + (size_t)n * C + c4) = make_float4(ax, ay, az, aw);
    }
}

// In-place per-row GEMM: h = h @ W + b. Each lane keeps W's column `lane`
// in 64 VGPRs; per row: 16 dwordx4 broadcast loads + 64 FMA, no LDS.
// Row owned by exactly one wave; all reads precede the store in wave order.
__global__ __launch_bounds__(256) void k_gemm_ip(
    float* __restrict__ h, const float* __restrict__ W, const float* __restrict__ b)
{
    int tid = threadIdx.x;
    int lane = tid & 63;
    float wreg[64];
    #pragma unroll
    for (int k = 0; k < 64; ++k) wreg[k] = W[k * C + lane];
    float bl = b[lane];
    int wv = (blockIdx.x * 256 + tid) >> 6;
    int nW = gridDim.x * 4;
    for (int row = wv; row < NC; row += nW) {
        float* ar = h + (size_t)row * C;
        float acc = bl;
        #pragma unroll
        for (int kk = 0; kk < 16; ++kk) {
            float4 a4 = *(const float4*)(ar + 4 * kk);
            acc = fmaf(a4.x, wreg[4 * kk + 0], acc);
            acc = fmaf(a4.y, wreg[4 * kk + 1], acc);
            acc = fmaf(a4.z, wreg[4 * kk + 2], acc);
            acc = fmaf(a4.w, wreg[4 * kk + 3], acc);
        }
        ar[lane] = acc;
    }
}

__global__ __launch_bounds__(256) void k_inv(
    const int* __restrict__ fwd, int* __restrict__ inv)
{
    int i = blockIdx.x * 256 + threadIdx.x;
    if (i < NC) inv[fwd[i]] = i;
}

__global__ __launch_bounds__(256) void k_gather_fine(
    const float* __restrict__ h, const int2* __restrict__ rec,
    const int* __restrict__ startF, const int* __restrict__ inv,
    float* __restrict__ out)
{
    int tid = threadIdx.x;
    int lane = tid & 63;
    int q = lane >> 4;
    int c4 = (lane & 15) << 2;
    int wv = (blockIdx.x * 256 + tid) >> 6;
    int nW = gridDim.x * 4;
    for (int m = wv; m < NF; m += nW) {
        int iv = inv[m];
        if (iv >= 0) {          // injection: copy h row, skip edges
            if (q == 0) {
                float4 v = *(const float4*)(h + (size_t)iv * C + c4);
                *(float4*)(out + (size_t)m * C + c4) = v;
            }
            continue;
        }
        int s = startF[m], e = startF[m + 1];
        float ax = 0.f, ay = 0.f, az = 0.f, aw = 0.f;
        for (int j = s + 2 * q; j < e; j += 8) {
            int2 r0 = rec[j];
            int j1 = j + 1;
            int2 r1 = (j1 < e) ? rec[j1] : make_int2(0, 0);
            float4 v0 = *(const float4*)(h + (size_t)r0.x * C + c4);
            float w0 = __int_as_float(r0.y);
            ax = fmaf(w0, v0.x, ax); ay = fmaf(w0, v0.y, ay);
            az = fmaf(w0, v0.z, az); aw = fmaf(w0, v0.w, aw);
            if (j1 < e) {
                float4 v1 = *(const float4*)(h + (size_t)r1.x * C + c4);
                float w1 = __int_as_float(r1.y);
                ax = fmaf(w1, v1.x, ax); ay = fmaf(w1, v1.y, ay);
                az = fmaf(w1, v1.z, az); aw = fmaf(w1, v1.w, aw);
            }
        }
        ax += __shfl_xor(ax, 16); ay += __shfl_xor(ay, 16);
        az += __shfl_xor(az, 16); aw += __shfl_xor(aw, 16);
        ax += __shfl_xor(ax, 32); ay += __shfl_xor(ay, 32);
        az += __shfl_xor(az, 32); aw += __shfl_xor(aw, 32);
        if (q == 0)
            *(float4*)(out + (size_t)m * C + c4) = make_float4(ax, ay, az, aw);
    }
}

extern "C" void kernel_launch(void* const* d_in, const int* in_sizes, int n_in,
                              void* d_out, int out_size, void* d_ws, size_t ws_size,
                              hipStream_t stream) {
    const float* x    = (const float*)d_in[0];
    const float* W    = (const float*)d_in[1];
    const float* b    = (const float*)d_in[2];
    const int*   ei   = (const int*)d_in[3];   // [2,E]: src = ei, dst = ei+NE
    const float* ea   = (const float*)d_in[4];
    const int*   psrc = (const int*)d_in[5];
    const int*   pdst = (const int*)d_in[6];
    const float* pw   = (const float*)d_in[7];
    const int*   fwd  = (const int*)d_in[8];
    float* out = (float*)d_out;

    // Workspace (~55.3 MB): h | rec | start | cnt(/inv) | chunks | choff
    char* p = (char*)d_ws;
    float* h      = (float*)p;  p += (size_t)NC * C * sizeof(float);     // 25.6 MB
    int2*  rec    = (int2*)p;   p += (size_t)(2 * NE) * sizeof(int2);    // 25.6 MB
    int*   start  = (int*)p;    p += (size_t)(NT + 1) * sizeof(int);     // 2.0 MB
    int*   cnt    = (int*)p;    p += (size_t)NT * sizeof(int);           // 2.0 MB
    int*   inv    = cnt;        // reused after k_place2 is done (NF <= NT)
    int*   chunks = (int*)p;    p += 512 * sizeof(int);
    int*   choff  = (int*)p;

    const int GS = 2048;                        // 8 blocks/CU persistent grids
    const int nChunks = (NT + 1023) / 1024;     // 489 <= 512

    // CSR build (combined coarse+fine)
    hipMemsetAsync(cnt, 0, (size_t)NT * sizeof(int), stream);
    k_hist2<<<GS, 256, 0, stream>>>(ei + NE, pdst, cnt);
    k_chunk_sum<<<nChunks, 256, 0, stream>>>(cnt, NT, chunks);
    k_scan_chunks<<<1, 512, 0, stream>>>(chunks, choff, nChunks);
    k_scan_final<<<nChunks, 256, 0, stream>>>(cnt, choff, start, NT, 2 * NE);
    hipMemsetAsync(cnt, 0, (size_t)NT * sizeof(int), stream);
    k_place2<<<GS, 256, 0, stream>>>(ei + NE, ei, ea, pdst, psrc, pw, start, cnt, rec);

    // inv map (cnt buffer is dead now)
    hipMemsetAsync(inv, 0xFF, (size_t)NF * sizeof(int), stream);
    k_inv<<<(NC + 255) / 256, 256, 0, stream>>>(fwd, inv);

    // Stage 1: agg = scatter(x) via CSR gather, then in-place GEMM -> h
    k_gather_coarse<<<GS, 256, 0, stream>>>(x, rec, start, h);
    k_gemm_ip<<<GS, 256, 0, stream>>>(h, W, b);

    // Stage 2: fine gather + injection -> out
    k_gather_fine<<<GS, 256, 0, stream>>>(h, rec, start + NC, inv, out);
}

// Round 5
// 661.675 us; speedup vs baseline: 4.4262x; 1.0175x over previous
//
#include <hip/hip_runtime.h>

#define NC 100000
#define NF 400000
#define NE 1600000
#define NT (NC + NF)            // 500000 combined nodes
#define C  64

// Combined node space: coarse dst -> [0, NC); fine dst -> [NC, NC+NF).
// 8 ranges of equal edge mass: coarse split at 25k nodes (deg~16),
// fine at 100k (deg~4). blockIdx%8 -> range (XCD round-robin heuristic):
// each range's rec slice (~3.2MB) and cnt slice stay hot in one XCD's L2.

// ---------------- Partitioned histogram ----------------
__global__ __launch_bounds__(256) void k_hist_part(
    const int* __restrict__ cd, const int* __restrict__ pd,
    int* __restrict__ cnt)
{
    int grp = blockIdx.x & 7;
    int stride = (gridDim.x >> 3) * 256;
    int t0 = (blockIdx.x >> 3) * 256 + threadIdx.x;
    if (grp < 4) {
        int lo = grp * 25000, hi = lo + 25000;
        for (int e = t0; e < NE; e += stride) {
            int d = cd[e];
            if (d >= lo && d < hi) atomicAdd(&cnt[d], 1);
        }
    } else {
        int lo = (grp - 4) * 100000, hi = lo + 100000;
        for (int e = t0; e < NE; e += stride) {
            int d = pd[e];
            if (d >= lo && d < hi) atomicAdd(&cnt[NC + d], 1);
        }
    }
}

// ---------------- Scan (unchanged) ----------------
__global__ __launch_bounds__(256) void k_chunk_sum(
    const int* __restrict__ cnt, int n, int* __restrict__ chunks)
{
    __shared__ int sd[256];
    int t = threadIdx.x;
    int base = blockIdx.x * 1024 + t * 4;
    int s = 0;
    #pragma unroll
    for (int i = 0; i < 4; ++i) if (base + i < n) s += cnt[base + i];
    sd[t] = s; __syncthreads();
    for (int off = 128; off > 0; off >>= 1) {
        if (t < off) sd[t] += sd[t + off];
        __syncthreads();
    }
    if (t == 0) chunks[blockIdx.x] = sd[0];
}

__global__ __launch_bounds__(512) void k_scan_chunks(
    const int* __restrict__ chunks, int* __restrict__ chunkoff, int nChunks)
{
    __shared__ int sd[512];
    int t = threadIdx.x;
    int v = (t < nChunks) ? chunks[t] : 0;
    sd[t] = v; __syncthreads();
    for (int off = 1; off < 512; off <<= 1) {
        int tv = sd[t];
        if (t >= off) tv += sd[t - off];
        __syncthreads();
        sd[t] = tv; __syncthreads();
    }
    if (t < nChunks) chunkoff[t] = sd[t] - v;   // exclusive
}

__global__ __launch_bounds__(256) void k_scan_final(
    const int* __restrict__ cnt, const int* __restrict__ chunkoff,
    int* __restrict__ start, int n, int nE)
{
    __shared__ int sd[256];
    int t = threadIdx.x;
    int base = blockIdx.x * 1024 + t * 4;
    int v[4];
    #pragma unroll
    for (int i = 0; i < 4; ++i) v[i] = (base + i < n) ? cnt[base + i] : 0;
    int tsum = v[0] + v[1] + v[2] + v[3];
    sd[t] = tsum; __syncthreads();
    for (int off = 1; off < 256; off <<= 1) {
        int tv = sd[t];
        if (t >= off) tv += sd[t - off];
        __syncthreads();
        sd[t] = tv; __syncthreads();
    }
    int off = chunkoff[blockIdx.x] + sd[t] - tsum;
    #pragma unroll
    for (int i = 0; i < 4; ++i) {
        if (base + i < n) { start[base + i] = off; off += v[i]; }
    }
    if (blockIdx.x == 0 && t == 0) start[n] = nE;
}

// cursor <- start  (place consumes cursor, gathers keep start)
__global__ __launch_bounds__(256) void k_copy(
    const int* __restrict__ src, int* __restrict__ dst, int n)
{
    int i = blockIdx.x * 256 + threadIdx.x;
    if (i < n) dst[i] = src[i];
}

// ---------------- Partitioned place ----------------
__global__ __launch_bounds__(256) void k_place_part(
    const int* __restrict__ cd, const int* __restrict__ csrc, const float* __restrict__ cw,
    const int* __restrict__ pd, const int* __restrict__ psrc, const float* __restrict__ pw,
    int* __restrict__ cursor, int2* __restrict__ rec)
{
    int grp = blockIdx.x & 7;
    int stride = (gridDim.x >> 3) * 256;
    int t0 = (blockIdx.x >> 3) * 256 + threadIdx.x;
    if (grp < 4) {
        int lo = grp * 25000, hi = lo + 25000;
        for (int e = t0; e < NE; e += stride) {
            int d = cd[e];
            if (d >= lo && d < hi) {
                int p = atomicAdd(&cursor[d], 1);
                rec[p] = make_int2(csrc[e], __float_as_int(cw[e]));
            }
        }
    } else {
        int lo = (grp - 4) * 100000, hi = lo + 100000;
        for (int e = t0; e < NE; e += stride) {
            int d = pd[e];
            if (d >= lo && d < hi) {
                int p = atomicAdd(&cursor[NC + d], 1);
                rec[p] = make_int2(psrc[e], __float_as_int(pw[e]));
            }
        }
    }
}

// ---------------- Gathers (unchanged from round 4) ----------------
__global__ __launch_bounds__(256) void k_gather_coarse(
    const float* __restrict__ x, const int2* __restrict__ rec,
    const int* __restrict__ start, float* __restrict__ agg)
{
    int tid = threadIdx.x;
    int lane = tid & 63;
    int q = lane >> 4;
    int c4 = (lane & 15) << 2;
    int wv = (blockIdx.x * 256 + tid) >> 6;
    int nW = gridDim.x * 4;
    for (int n = wv; n < NC; n += nW) {
        int s = start[n], e = start[n + 1];
        float ax = 0.f, ay = 0.f, az = 0.f, aw = 0.f;
        for (int j = s + 2 * q; j < e; j += 8) {
            int2 r0 = rec[j];
            int j1 = j + 1;
            int2 r1 = (j1 < e) ? rec[j1] : make_int2(0, 0);
            float4 v0 = *(const float4*)(x + (size_t)r0.x * C + c4);
            float w0 = __int_as_float(r0.y);
            ax = fmaf(w0, v0.x, ax); ay = fmaf(w0, v0.y, ay);
            az = fmaf(w0, v0.z, az); aw = fmaf(w0, v0.w, aw);
            if (j1 < e) {
                float4 v1 = *(const float4*)(x + (size_t)r1.x * C + c4);
                float w1 = __int_as_float(r1.y);
                ax = fmaf(w1, v1.x, ax); ay = fmaf(w1, v1.y, ay);
                az = fmaf(w1, v1.z, az); aw = fmaf(w1, v1.w, aw);
            }
        }
        ax += __shfl_xor(ax, 16); ay += __shfl_xor(ay, 16);
        az += __shfl_xor(az, 16); aw += __shfl_xor(aw, 16);
        ax += __shfl_xor(ax, 32); ay += __shfl_xor(ay, 32);
        az += __shfl_xor(az, 32); aw += __shfl_xor(aw, 32);
        if (q == 0)
            *(float4*)(agg + (size_t)n * C + c4) = make_float4(ax, ay, az, aw);
    }
}

__global__ __launch_bounds__(256) void k_gemm_ip(
    float* __restrict__ h, const float* __restrict__ W, const float* __restrict__ b)
{
    int tid = threadIdx.x;
    int lane = tid & 63;
    float wreg[64];
    #pragma unroll
    for (int k = 0; k < 64; ++k) wreg[k] = W[k * C + lane];
    float bl = b[lane];
    int wv = (blockIdx.x * 256 + tid) >> 6;
    int nW = gridDim.x * 4;
    for (int row = wv; row < NC; row += nW) {
        float* ar = h + (size_t)row * C;
        float acc = bl;
        #pragma unroll
        for (int kk = 0; kk < 16; ++kk) {
            float4 a4 = *(const float4*)(ar + 4 * kk);
            acc = fmaf(a4.x, wreg[4 * kk + 0], acc);
            acc = fmaf(a4.y, wreg[4 * kk + 1], acc);
            acc = fmaf(a4.z, wreg[4 * kk + 2], acc);
            acc = fmaf(a4.w, wreg[4 * kk + 3], acc);
        }
        ar[lane] = acc;
    }
}

__global__ __launch_bounds__(256) void k_inv(
    const int* __restrict__ fwd, int* __restrict__ inv)
{
    int i = blockIdx.x * 256 + threadIdx.x;
    if (i < NC) inv[fwd[i]] = i;
}

__global__ __launch_bounds__(256) void k_gather_fine(
    const float* __restrict__ h, const int2* __restrict__ rec,
    const int* __restrict__ startF, const int* __restrict__ inv,
    float* __restrict__ out)
{
    int tid = threadIdx.x;
    int lane = tid & 63;
    int q = lane >> 4;
    int c4 = (lane & 15) << 2;
    int wv = (blockIdx.x * 256 + tid) >> 6;
    int nW = gridDim.x * 4;
    for (int m = wv; m < NF; m += nW) {
        int iv = inv[m];
        if (iv >= 0) {          // injection: copy h row, skip edges
            if (q == 0) {
                float4 v = *(const float4*)(h + (size_t)iv * C + c4);
                *(float4*)(out + (size_t)m * C + c4) = v;
            }
            continue;
        }
        int s = startF[m], e = startF[m + 1];
        float ax = 0.f, ay = 0.f, az = 0.f, aw = 0.f;
        for (int j = s + 2 * q; j < e; j += 8) {
            int2 r0 = rec[j];
            int j1 = j + 1;
            int2 r1 = (j1 < e) ? rec[j1] : make_int2(0, 0);
            float4 v0 = *(const float4*)(h + (size_t)r0.x * C + c4);
            float w0 = __int_as_float(r0.y);
            ax = fmaf(w0, v0.x, ax); ay = fmaf(w0, v0.y, ay);
            az = fmaf(w0, v0.z, az); aw = fmaf(w0, v0.w, aw);
            if (j1 < e) {
                float4 v1 = *(const float4*)(h + (size_t)r1.x * C + c4);
                float w1 = __int_as_float(r1.y);
                ax = fmaf(w1, v1.x, ax); ay = fmaf(w1, v1.y, ay);
                az = fmaf(w1, v1.z, az); aw = fmaf(w1, v1.w, aw);
            }
        }
        ax += __shfl_xor(ax, 16); ay += __shfl_xor(ay, 16);
        az += __shfl_xor(az, 16); aw += __shfl_xor(aw, 16);
        ax += __shfl_xor(ax, 32); ay += __shfl_xor(ay, 32);
        az += __shfl_xor(az, 32); aw += __shfl_xor(aw, 32);
        if (q == 0)
            *(float4*)(out + (size_t)m * C + c4) = make_float4(ax, ay, az, aw);
    }
}

extern "C" void kernel_launch(void* const* d_in, const int* in_sizes, int n_in,
                              void* d_out, int out_size, void* d_ws, size_t ws_size,
                              hipStream_t stream) {
    const float* x    = (const float*)d_in[0];
    const float* W    = (const float*)d_in[1];
    const float* b    = (const float*)d_in[2];
    const int*   ei   = (const int*)d_in[3];   // [2,E]: src = ei, dst = ei+NE
    const float* ea   = (const float*)d_in[4];
    const int*   psrc = (const int*)d_in[5];
    const int*   pdst = (const int*)d_in[6];
    const float* pw   = (const float*)d_in[7];
    const int*   fwd  = (const int*)d_in[8];
    float* out = (float*)d_out;

    // Workspace (~55.3 MB): h | rec | start | cnt(/inv) | chunks | choff
    char* p = (char*)d_ws;
    float* h      = (float*)p;  p += (size_t)NC * C * sizeof(float);     // 25.6 MB
    int2*  rec    = (int2*)p;   p += (size_t)(2 * NE) * sizeof(int2);    // 25.6 MB
    int*   start  = (int*)p;    p += (size_t)(NT + 1) * sizeof(int);     // 2.0 MB
    int*   cnt    = (int*)p;    p += (size_t)NT * sizeof(int);           // 2.0 MB
    int*   inv    = cnt;        // reused after k_place_part retires cursor
    int*   chunks = (int*)p;    p += 512 * sizeof(int);
    int*   choff  = (int*)p;

    const int GS = 2048;                        // 8 blocks/CU persistent grids
    const int nChunks = (NT + 1023) / 1024;     // 489 <= 512

    // CSR build (combined coarse+fine), dst-range partitioned by blockIdx%8
    hipMemsetAsync(cnt, 0, (size_t)NT * sizeof(int), stream);
    k_hist_part<<<GS, 256, 0, stream>>>(ei + NE, pdst, cnt);
    k_chunk_sum<<<nChunks, 256, 0, stream>>>(cnt, NT, chunks);
    k_scan_chunks<<<1, 512, 0, stream>>>(chunks, choff, nChunks);
    k_scan_final<<<nChunks, 256, 0, stream>>>(cnt, choff, start, NT, 2 * NE);
    k_copy<<<(NT + 255) / 256, 256, 0, stream>>>(start, cnt, NT);   // cursor
    k_place_part<<<GS, 256, 0, stream>>>(ei + NE, ei, ea, pdst, psrc, pw, cnt, rec);

    // inv map (cursor buffer is dead now)
    hipMemsetAsync(inv, 0xFF, (size_t)NF * sizeof(int), stream);
    k_inv<<<(NC + 255) / 256, 256, 0, stream>>>(fwd, inv);

    // Stage 1: agg = scatter(x) via CSR gather, then in-place GEMM -> h
    k_gather_coarse<<<GS, 256, 0, stream>>>(x, rec, start, h);
    k_gemm_ip<<<GS, 256, 0, stream>>>(h, W, b);

    // Stage 2: fine gather + injection -> out
    k_gather_fine<<<GS, 256, 0, stream>>>(h, rec, start + NC, inv, out);
}